// Round 4
// baseline (88.621 us; speedup 1.0000x reference)
//
#include <hip/hip_runtime.h>
#include <hip/hip_bf16.h>

#define EPS 1e-8f

typedef __attribute__((ext_vector_type(8))) short short8;
typedef __attribute__((ext_vector_type(4))) float f32x4;
typedef __attribute__((ext_vector_type(16))) float f32x16;

__device__ __forceinline__ unsigned short f2bf(float f) {
  union { float f; unsigned u; } v; v.f = f;
  unsigned r = v.u + 0x7fffu + ((v.u >> 16) & 1u);
  return (unsigned short)(r >> 16);
}
__device__ __forceinline__ float bf2f(unsigned short b) {
  union { unsigned u; float f; } v; v.u = ((unsigned)b) << 16;
  return v.f;
}
__device__ __forceinline__ unsigned pack_bf2(float lo, float hi) {
  unsigned r;
  asm("v_cvt_pk_bf16_f32 %0, %1, %2" : "=v"(r) : "v"(lo), "v"(hi));
  return r;
}

// ---------------- k0: build bf16 transposed weights --------------------------
__global__ __launch_bounds__(256) void k0_prep(const float* __restrict__ We1,
                                               const float* __restrict__ We2,
                                               const float* __restrict__ Wg1,
                                               const float* __restrict__ Wg2,
                                               const float* __restrict__ Wf,
                                               unsigned short* __restrict__ We1T,
                                               unsigned short* __restrict__ We2T,
                                               unsigned short* __restrict__ Wg1T,
                                               unsigned short* __restrict__ Wg2T,
                                               unsigned short* __restrict__ WfT) {
  int idx = blockIdx.x * 256 + threadIdx.x;     // 655360 total
  if (idx < 262144) {
    int n = idx >> 10, k = idx & 1023;
    We1T[idx] = f2bf(We1[k * 256 + n]);
  } else if (idx < 294912) {
    int e = idx - 262144;
    int n = e >> 8, k = e & 255;
    We2T[e] = f2bf(We2[k * 128 + n]);
  } else if (idx < 458752) {
    int e = idx - 294912;
    int n = e / 160, c = e % 160;
    float v = 0.f;
    if (c < 129) v = (n < 512) ? Wg1[c * 512 + n] : Wg1[(129 + c) * 512 + (n - 512)];
    Wg1T[e] = f2bf(v);
  } else if (idx < 589824) {
    int e = idx - 458752;
    int n = e >> 9, k = e & 511;
    Wg2T[e] = f2bf(Wg2[k * 256 + n]);
  } else {
    int e = idx - 589824;
    int n = e >> 8, k = e & 255;
    WfT[e] = f2bf(Wf[k * 256 + n]);
  }
}

// ---------------- k1: h_bf = bf16(relu(x @ We1 + be1)) -----------------------
__global__ __launch_bounds__(512, 2) void k1(const float* __restrict__ x,
                                             const unsigned short* __restrict__ We1T,
                                             const float* __restrict__ be1,
                                             unsigned short* __restrict__ h_bf) {
  __shared__ unsigned char As[2][8192];   // [16][256] bf16, swizzled
  int tid = threadIdx.x, lane = tid & 63, w = tid >> 6;
  int m0 = blockIdx.x * 16;
  int srow = tid >> 5, skk = (tid & 31) * 8;
  int cb = w * 32;
  int row = lane & 15, kg = (lane >> 4) * 8;

  f32x4 acc[2] = {{0,0,0,0},{0,0,0,0}};

  auto stage = [&](int kc, int buf) {
    const float* src = x + (size_t)(m0 + srow) * 1024 + kc * 256 + skk;
    float4 a = *reinterpret_cast<const float4*>(src);
    float4 b = *reinterpret_cast<const float4*>(src + 4);
    uint4 pv;
    pv.x = pack_bf2(a.x, a.y); pv.y = pack_bf2(a.z, a.w);
    pv.z = pack_bf2(b.x, b.y); pv.w = pack_bf2(b.z, b.w);
    int addr = (srow * 512 + skk * 2) ^ ((srow & 7) << 4);
    *reinterpret_cast<uint4*>(&As[buf][addr]) = pv;
  };

  stage(0, 0);
  __syncthreads();
  for (int kc = 0; kc < 4; ++kc) {
    if (kc < 3) stage(kc + 1, (kc + 1) & 1);
    short8 breg[2][8];
#pragma unroll
    for (int cf = 0; cf < 2; ++cf)
#pragma unroll
      for (int ks = 0; ks < 8; ++ks)
        breg[cf][ks] = *reinterpret_cast<const short8*>(
            We1T + (size_t)(cb + cf * 16 + row) * 1024 + kc * 256 + ks * 32 + kg);
    const unsigned char* hc = &As[kc & 1][0];
#pragma unroll
    for (int ks = 0; ks < 8; ++ks) {
      int aoff = (row * 512 + ks * 64 + kg * 2) ^ ((row & 7) << 4);
      short8 af = *reinterpret_cast<const short8*>(hc + aoff);
      acc[0] = __builtin_amdgcn_mfma_f32_16x16x32_bf16(af, breg[0][ks], acc[0], 0, 0, 0);
      acc[1] = __builtin_amdgcn_mfma_f32_16x16x32_bf16(af, breg[1][ks], acc[1], 0, 0, 0);
    }
    __syncthreads();
  }
#pragma unroll
  for (int cf = 0; cf < 2; ++cf) {
    int col = cb + cf * 16 + row;
    float bias = be1[col];
#pragma unroll
    for (int r = 0; r < 4; ++r) {
      int orow = m0 + (lane >> 4) * 4 + r;
      h_bf[(size_t)orow * 256 + col] = f2bf(fmaxf(acc[cf][r] + bias, 0.f));
    }
  }
}

// ---------------- k2: fused z=h@We2+be2 -> LN(T) -> zc(LDS) -> g_all quarter -
// grid 512 = (b 128) x (nq 4), 256 thr = 4 waves. Each block redoes the tiny
// z+LN (2 MFLOP) and computes N-quarter [nq*256, nq*256+256) of zc @ Wg1T.
__global__ __launch_bounds__(256) void k2(const unsigned short* __restrict__ h_bf,
                                          const unsigned short* __restrict__ We2T,
                                          const float* __restrict__ be2,
                                          const float* __restrict__ gamma,
                                          const float* __restrict__ beta,
                                          const unsigned short* __restrict__ Wg1T,
                                          const float* __restrict__ bg1,
                                          unsigned short* __restrict__ g_all) {
  __shared__ unsigned char zcs[16384];   // [32][256] bf16 swizzled: h tile, then zc
  __shared__ float zb[32][132];
  int b = blockIdx.x >> 2, nq = blockIdx.x & 3;
  int tid = threadIdx.x, lane = tid & 63, w = tid >> 6;
  int row = lane & 15, kg = (lane >> 4) * 8;

  // ---- phase A: stage h[b] (32x256 bf16) into LDS
  {
    int srow = tid >> 3, skk = (tid & 7) * 32;
#pragma unroll
    for (int q = 0; q < 4; ++q) {
      short8 v = *reinterpret_cast<const short8*>(
          h_bf + (size_t)(b * 32 + srow) * 256 + skk + q * 8);
      int addr = (srow * 512 + (skk + q * 8) * 2) ^ ((srow & 7) << 4);
      *reinterpret_cast<short8*>(&zcs[addr]) = v;
    }
  }
  short8 breg1[2][8];
#pragma unroll
  for (int cf = 0; cf < 2; ++cf)
#pragma unroll
    for (int ks = 0; ks < 8; ++ks)
      breg1[cf][ks] = *reinterpret_cast<const short8*>(
          We2T + (size_t)(w * 32 + cf * 16 + row) * 256 + ks * 32 + kg);
  __syncthreads();

  // ---- phase B: z = h @ We2 + be2  (32x128)
  {
    f32x4 acc[2][2] = {{{0,0,0,0},{0,0,0,0}},{{0,0,0,0},{0,0,0,0}}};
#pragma unroll
    for (int ks = 0; ks < 8; ++ks) {
      int a0off = (row * 512 + ks * 64 + kg * 2) ^ ((row & 7) << 4);
      int a1off = ((16 + row) * 512 + ks * 64 + kg * 2) ^ ((row & 7) << 4);
      short8 a0 = *reinterpret_cast<const short8*>(&zcs[a0off]);
      short8 a1 = *reinterpret_cast<const short8*>(&zcs[a1off]);
#pragma unroll
      for (int cf = 0; cf < 2; ++cf) {
        acc[0][cf] = __builtin_amdgcn_mfma_f32_16x16x32_bf16(a0, breg1[cf][ks], acc[0][cf], 0, 0, 0);
        acc[1][cf] = __builtin_amdgcn_mfma_f32_16x16x32_bf16(a1, breg1[cf][ks], acc[1][cf], 0, 0, 0);
      }
    }
#pragma unroll
    for (int rf = 0; rf < 2; ++rf)
#pragma unroll
      for (int cf = 0; cf < 2; ++cf) {
        int col = w * 32 + cf * 16 + row;
        float bias = be2[col];
#pragma unroll
        for (int r = 0; r < 4; ++r)
          zb[rf * 16 + (lane >> 4) * 4 + r][col] = acc[rf][cf][r] + bias;
      }
  }
  __syncthreads();

  // ---- phase C: LN over T (ddof=1), zc -> LDS (cols 0..159: z|tag|pad)
  if (tid < 128) {
    float s = 0.f, s2 = 0.f;
#pragma unroll 4
    for (int t = 0; t < 32; ++t) { float v = zb[t][tid]; s += v; s2 += v * v; }
    float mu = s * (1.f / 32.f);
    float var = (s2 - 32.f * mu * mu) * (1.f / 31.f);
    float rs = 1.f / sqrtf(fmaxf(var, 0.f) + EPS);
    float g = gamma[tid], be = beta[tid];
#pragma unroll 4
    for (int t = 0; t < 32; ++t) {
      unsigned short v = f2bf((zb[t][tid] - mu) * rs * g + be);
      int addr = (t * 512 + tid * 2) ^ ((t & 7) << 4);
      *reinterpret_cast<unsigned short*>(&zcs[addr]) = v;
    }
  } else if (tid < 160) {
    for (int t = 0; t < 32; ++t) {
      unsigned short v = (tid == 128) ? f2bf((float)t) : 0;
      int addr = (t * 512 + tid * 2) ^ ((t & 7) << 4);
      *reinterpret_cast<unsigned short*>(&zcs[addr]) = v;
    }
  }
  __syncthreads();

  // ---- phase D: g quarter = zc @ Wg1T  (N=256 per block, K=160)
  {
    int n0 = nq * 256 + w * 64;
    short8 af[2][5];
#pragma unroll
    for (int rf = 0; rf < 2; ++rf)
#pragma unroll
      for (int ks = 0; ks < 5; ++ks) {
        int aoff = ((rf * 16 + row) * 512 + ks * 64 + kg * 2) ^ ((row & 7) << 4);
        af[rf][ks] = *reinterpret_cast<const short8*>(&zcs[aoff]);
      }
    short8 breg[4][5];
#pragma unroll
    for (int cf = 0; cf < 4; ++cf)
#pragma unroll
      for (int ks = 0; ks < 5; ++ks)
        breg[cf][ks] = *reinterpret_cast<const short8*>(
            Wg1T + (size_t)(n0 + cf * 16 + row) * 160 + ks * 32 + kg);
    f32x4 acc[2][4] = {{{0,0,0,0},{0,0,0,0},{0,0,0,0},{0,0,0,0}},
                       {{0,0,0,0},{0,0,0,0},{0,0,0,0},{0,0,0,0}}};
#pragma unroll
    for (int ks = 0; ks < 5; ++ks)
#pragma unroll
      for (int cf = 0; cf < 4; ++cf) {
        acc[0][cf] = __builtin_amdgcn_mfma_f32_16x16x32_bf16(af[0][ks], breg[cf][ks], acc[0][cf], 0, 0, 0);
        acc[1][cf] = __builtin_amdgcn_mfma_f32_16x16x32_bf16(af[1][ks], breg[cf][ks], acc[1][cf], 0, 0, 0);
      }
#pragma unroll
    for (int cf = 0; cf < 4; ++cf) {
      int n = n0 + cf * 16 + row;
      float bias = (n < 512) ? bg1[n] : 0.f;
#pragma unroll
      for (int rf = 0; rf < 2; ++rf)
#pragma unroll
        for (int r = 0; r < 4; ++r) {
          int t = rf * 16 + (lane >> 4) * 4 + r;
          g_all[((size_t)(b * 32 + t) << 10) + n] = f2bf(acc[rf][cf][r] + bias);
        }
    }
  }
}

// ---------------- k3: all_gp[hi][b] = sum over (ii in half, j) ---------------
// 32x32x16 MFMA, B (Wg2T, 32 cols x K=512) in regs, 4-deep A-read ring.
__global__ __launch_bounds__(512, 2) void k3(const unsigned short* __restrict__ g_all,
                                             const unsigned short* __restrict__ Wg2T,
                                             const float* __restrict__ bg2,
                                             float* __restrict__ all_gp) {
  __shared__ unsigned char ldsH[2][32768];   // [32][512] bf16 swizzled, dbuf
  int b = blockIdx.x >> 1, hi = blockIdx.x & 1;
  int ii0 = hi * 16;
  int tid = threadIdx.x, lane = tid & 63, w = tid >> 6;
  int l31 = lane & 31, lhi = lane >> 5;
  int cb = w * 32;
  int p = tid >> 4, kslot = tid & 15;

  // B-regs: step s covers K [s*16, s*16+16); lane: col cb+l31, k = s*16+lhi*8..+8
  short8 breg[32];
#pragma unroll
  for (int s = 0; s < 32; ++s)
    breg[s] = *reinterpret_cast<const short8*>(
        Wg2T + (size_t)(cb + l31) * 512 + s * 16 + lhi * 8);

  // gj cache (fp32): thread covers row p, elements kslot*8 + q*128 + e
  float gjf[32];
  {
    const unsigned short* gjp = g_all + ((size_t)(b * 32 + p) << 10) + 512 + kslot * 8;
#pragma unroll
    for (int q = 0; q < 4; ++q) {
      short8 gv0 = *reinterpret_cast<const short8*>(gjp + q * 128);
#pragma unroll
      for (int e = 0; e < 8; ++e) gjf[q * 8 + e] = bf2f((unsigned short)gv0[e]);
    }
  }
  float bias = bg2[cb + l31];
  float accsum = 0.f;

  short8 gv[4];   // gi loads issued early, consumed after MFMA loop
  auto hload = [&](int ii) {
    const unsigned short* gi = g_all + ((size_t)(b * 32 + ii) << 10) + kslot * 8;
#pragma unroll
    for (int q = 0; q < 4; ++q)
      gv[q] = *reinterpret_cast<const short8*>(gi + q * 128);
  };
  auto hstore = [&](int buf) {
    unsigned char* hb = &ldsH[buf][0] + p * 1024;
#pragma unroll
    for (int q = 0; q < 4; ++q) {
      uint4 pv;
      float f0 = fmaxf(bf2f((unsigned short)gv[q][0]) + gjf[q * 8 + 0], 0.f);
      float f1 = fmaxf(bf2f((unsigned short)gv[q][1]) + gjf[q * 8 + 1], 0.f);
      float f2 = fmaxf(bf2f((unsigned short)gv[q][2]) + gjf[q * 8 + 2], 0.f);
      float f3 = fmaxf(bf2f((unsigned short)gv[q][3]) + gjf[q * 8 + 3], 0.f);
      float f4 = fmaxf(bf2f((unsigned short)gv[q][4]) + gjf[q * 8 + 4], 0.f);
      float f5 = fmaxf(bf2f((unsigned short)gv[q][5]) + gjf[q * 8 + 5], 0.f);
      float f6 = fmaxf(bf2f((unsigned short)gv[q][6]) + gjf[q * 8 + 6], 0.f);
      float f7 = fmaxf(bf2f((unsigned short)gv[q][7]) + gjf[q * 8 + 7], 0.f);
      pv.x = pack_bf2(f0, f1); pv.y = pack_bf2(f2, f3);
      pv.z = pack_bf2(f4, f5); pv.w = pack_bf2(f6, f7);
      int addr = (kslot * 16 + q * 256) ^ ((p & 7) << 4);
      *reinterpret_cast<uint4*>(hb + addr) = pv;
    }
  };

  hload(ii0);
  hstore(0);
  __syncthreads();

  for (int it = 0; it < 16; ++it) {
    if (it < 15) hload(ii0 + it + 1);     // global loads in flight across MFMA loop
    const unsigned char* hc = &ldsH[it & 1][0];
    f32x16 acc = {0.f,0.f,0.f,0.f,0.f,0.f,0.f,0.f,0.f,0.f,0.f,0.f,0.f,0.f,0.f,0.f};
    short8 ar[4];
#pragma unroll
    for (int s = 0; s < 4; ++s)
      ar[s] = *reinterpret_cast<const short8*>(
          hc + ((l31 * 1024 + s * 32 + lhi * 16) ^ ((l31 & 7) << 4)));
#pragma unroll
    for (int s = 0; s < 32; ++s) {
      short8 cur = ar[s & 3];
      if (s < 28)
        ar[s & 3] = *reinterpret_cast<const short8*>(
            hc + ((l31 * 1024 + (s + 4) * 32 + lhi * 16) ^ ((l31 & 7) << 4)));
      __builtin_amdgcn_s_setprio(1);
      acc = __builtin_amdgcn_mfma_f32_32x32x16_bf16(cur, breg[s], acc, 0, 0, 0);
      __builtin_amdgcn_s_setprio(0);
    }
    if (it < 15) hstore((it + 1) & 1);
#pragma unroll
    for (int r = 0; r < 16; ++r)
      accsum += fmaxf(acc[r] + bias, 0.f);
    __syncthreads();
  }

  accsum += __shfl_xor(accsum, 32, 64);
  if (lane < 32)
    all_gp[(size_t)(hi * 128 + b) * 256 + cb + l31] = accsum;
}

// ---------------- k4: head (MFMA) --------------------------------------------
__global__ __launch_bounds__(512) void k4(const float* __restrict__ all_gp,
                                          const unsigned short* __restrict__ WfT,
                                          const float* __restrict__ bfv,
                                          const float* __restrict__ Wy,
                                          const float* __restrict__ by,
                                          float* __restrict__ out) {
  __shared__ unsigned char As[8192];      // [16][256] bf16 swizzled
  __shared__ float fh[16][264];
  __shared__ float wys[1024];
  __shared__ float yvs[16][4];
  int tid = threadIdx.x, lane = tid & 63, w = tid >> 6;
  int row = lane & 15, kg = (lane >> 4) * 8;
  int m0 = blockIdx.x * 16;

  {
    int r = tid >> 5, c8 = (tid & 31) * 8;
    const float* p0 = all_gp + (size_t)(m0 + r) * 256 + c8;
    const float* p1 = all_gp + (size_t)(128 + m0 + r) * 256 + c8;
    float4 a0 = *reinterpret_cast<const float4*>(p0);
    float4 a1 = *reinterpret_cast<const float4*>(p0 + 4);
    float4 b0 = *reinterpret_cast<const float4*>(p1);
    float4 b1 = *reinterpret_cast<const float4*>(p1 + 4);
    uint4 pv;
    pv.x = pack_bf2(a0.x + b0.x, a0.y + b0.y);
    pv.y = pack_bf2(a0.z + b0.z, a0.w + b0.w);
    pv.z = pack_bf2(a1.x + b1.x, a1.y + b1.y);
    pv.w = pack_bf2(a1.z + b1.z, a1.w + b1.w);
    int addr = (r * 512 + c8 * 2) ^ ((r & 7) << 4);
    *reinterpret_cast<uint4*>(&As[addr]) = pv;
  }
  wys[tid] = Wy[tid];
  wys[tid + 512] = Wy[tid + 512];
  short8 breg[2][8];
#pragma unroll
  for (int cf = 0; cf < 2; ++cf)
#pragma unroll
    for (int ks = 0; ks < 8; ++ks)
      breg[cf][ks] = *reinterpret_cast<const short8*>(
          WfT + (size_t)(w * 32 + cf * 16 + row) * 256 + ks * 32 + kg);
  __syncthreads();

  f32x4 acc[2] = {{0,0,0,0},{0,0,0,0}};
#pragma unroll
  for (int ks = 0; ks < 8; ++ks) {
    int aoff = (row * 512 + ks * 64 + kg * 2) ^ ((row & 7) << 4);
    short8 af = *reinterpret_cast<const short8*>(&As[aoff]);
    acc[0] = __builtin_amdgcn_mfma_f32_16x16x32_bf16(af, breg[0][ks], acc[0], 0, 0, 0);
    acc[1] = __builtin_amdgcn_mfma_f32_16x16x32_bf16(af, breg[1][ks], acc[1], 0, 0, 0);
  }
#pragma unroll
  for (int cf = 0; cf < 2; ++cf) {
    int col = w * 32 + cf * 16 + row;
    float bias = bfv[col];
#pragma unroll
    for (int r = 0; r < 4; ++r)
      fh[(lane >> 4) * 4 + r][col] = fmaxf(acc[cf][r] + bias, 0.f);
  }
  __syncthreads();

  if (tid < 64) {
    int r = tid >> 2, o = tid & 3;
    float y = by[o];
#pragma unroll 4
    for (int k = 0; k < 256; ++k) y += fh[r][k] * wys[k * 4 + o];
    yvs[r][o] = y;
    out[(m0 + r) * 4 + o] = y;
  }
  __syncthreads();
  if (tid < 16) {
    int am = 0;
    float best = yvs[tid][0];
#pragma unroll
    for (int o = 1; o < 4; ++o)
      if (yvs[tid][o] > best) { best = yvs[tid][o]; am = o; }
    out[512 + m0 + tid] = (float)am;
  }
}

extern "C" void kernel_launch(void* const* d_in, const int* in_sizes, int n_in,
                              void* d_out, int out_size, void* d_ws, size_t ws_size,
                              hipStream_t stream) {
  const float* x     = (const float*)d_in[0];
  const float* We1   = (const float*)d_in[1];
  const float* be1   = (const float*)d_in[2];
  const float* We2   = (const float*)d_in[3];
  const float* be2   = (const float*)d_in[4];
  const float* gamma = (const float*)d_in[5];
  const float* beta  = (const float*)d_in[6];
  const float* Wg1   = (const float*)d_in[7];
  const float* bg1   = (const float*)d_in[8];
  const float* Wg2   = (const float*)d_in[9];
  const float* bg2   = (const float*)d_in[10];
  const float* Wf    = (const float*)d_in[11];
  const float* bff   = (const float*)d_in[12];
  const float* Wy    = (const float*)d_in[13];
  const float* by    = (const float*)d_in[14];

  char* ws = (char*)d_ws;
  unsigned short* h_bf  = (unsigned short*)(ws + 0);          // 2 MB
  unsigned short* g_all = (unsigned short*)(ws + 2097152);    // 8 MB
  unsigned short* We1T  = (unsigned short*)(ws + 10485760);   // 512 KB
  unsigned short* We2T  = (unsigned short*)(ws + 11010048);   // 64 KB
  unsigned short* Wg1T  = (unsigned short*)(ws + 11075584);   // 320 KB
  unsigned short* Wg2T  = (unsigned short*)(ws + 11403264);   // 256 KB
  float*          all_gp= (float*)(ws + 11665408);            // 256 KB
  unsigned short* WfT   = (unsigned short*)(ws + 11927552);   // 128 KB
  float*          out   = (float*)d_out;

  k0_prep<<<2560, 256, 0, stream>>>(We1, We2, Wg1, Wg2, Wf, We1T, We2T, Wg1T, Wg2T, WfT);
  k1<<<256, 512, 0, stream>>>(x, We1T, be1, h_bf);
  k2<<<512, 256, 0, stream>>>(h_bf, We2T, be2, gamma, beta, Wg1T, bg1, g_all);
  k3<<<256, 512, 0, stream>>>(g_all, Wg2T, bg2, all_gp);
  k4<<<8, 512, 0, stream>>>(all_gp, WfT, bff, Wy, by, out);
}